// Round 9
// baseline (379.440 us; speedup 1.0000x reference)
//
#include <hip/hip_runtime.h>
#include <hip/hip_bf16.h>
#include <math.h>

// Problem constants: B=8, S=1000, E=1024, H=16, D=64
constexpr int B_ = 8, S_ = 1000, E_ = 1024, H_ = 16, D_ = 64;
constexpr int M_ = B_ * S_;   // 8000 rows

using bf16x8 = __attribute__((ext_vector_type(8))) __bf16;
using u16x8  = __attribute__((ext_vector_type(8))) unsigned short;
using f32x4  = __attribute__((ext_vector_type(4))) float;

static __device__ __forceinline__ unsigned short f2bf(float f) {
    union { float f; unsigned u; } c; c.f = f;
    return (unsigned short)((c.u + 0x7FFF + ((c.u >> 16) & 1)) >> 16);
}
static __device__ __forceinline__ unsigned short f2bf_fast(float f) {
    union { float f; unsigned u; } c; c.f = f;
    return (unsigned short)((c.u + 0x8000) >> 16);   // round-half-up
}
static __device__ __forceinline__ float bfr2f(unsigned short s) {
    union { unsigned u; float f; } c; c.u = ((unsigned)s) << 16;
    return c.f;
}

// ---------------------------------------------------------------------------
// Cast x (fp32 [M,E]) -> bf16.
// ---------------------------------------------------------------------------
__global__ __launch_bounds__(256) void cast_x_kernel(
    const float* __restrict__ x, unsigned short* __restrict__ xbf)
{
    const size_t i = ((size_t)blockIdx.x * 256 + threadIdx.x) * 4;
    float4 v = *(const float4*)(x + i);
    ushort4 o;
    o.x = f2bf(v.x); o.y = f2bf(v.y); o.z = f2bf(v.z); o.w = f2bf(v.w);
    *(ushort4*)(xbf + i) = o;
}

// ---------------------------------------------------------------------------
// Transpose+cast qkv weights: w[h][e][d] fp32 -> WT[(z*16+h)*64 + d][e] bf16.
// ---------------------------------------------------------------------------
__global__ __launch_bounds__(256) void transpose_wqkv_kernel(
    const float* __restrict__ wq, const float* __restrict__ wk,
    const float* __restrict__ wv, unsigned short* __restrict__ WT)
{
    __shared__ unsigned short Ts[64 * 65];
    const int et = blockIdx.x, zh = blockIdx.y;
    const int z = zh >> 4, h = zh & 15;
    const float* src = (z == 0 ? wq : z == 1 ? wk : wv) + (size_t)h * E_ * D_;

    const int d = threadIdx.x & 63;
    const int e0 = threadIdx.x >> 6;   // 0..3
    #pragma unroll
    for (int p = 0; p < 16; ++p) {
        const int e = e0 + p * 4;
        Ts[d * 65 + e] = f2bf(src[(size_t)(et * 64 + e) * D_ + d]);
    }
    __syncthreads();
    const int e = threadIdx.x & 63;
    const int d0 = threadIdx.x >> 6;
    #pragma unroll
    for (int p = 0; p < 16; ++p) {
        const int dd = d0 + p * 4;
        WT[((size_t)zh * 64 + dd) * E_ + et * 64 + e] = Ts[dd * 65 + e];
    }
}

// ---------------------------------------------------------------------------
// Transpose+cast wp: wp[e][f] fp32 -> wpT[f][e] bf16. grid (16 e, 16 f).
// ---------------------------------------------------------------------------
__global__ __launch_bounds__(256) void transpose_wp_kernel(
    const float* __restrict__ wp, unsigned short* __restrict__ wpT)
{
    __shared__ unsigned short Ts[64 * 65];
    const int et = blockIdx.x, ft = blockIdx.y;
    const int f = threadIdx.x & 63;
    const int e0 = threadIdx.x >> 6;
    #pragma unroll
    for (int p = 0; p < 16; ++p) {
        const int e = e0 + p * 4;
        Ts[f * 65 + e] = f2bf(wp[(size_t)(et * 64 + e) * E_ + ft * 64 + f]);
    }
    __syncthreads();
    const int e = threadIdx.x & 63;
    const int f0 = threadIdx.x >> 6;
    #pragma unroll
    for (int p = 0; p < 16; ++p) {
        const int ff = f0 + p * 4;
        wpT[((size_t)(ft * 64 + ff)) * E_ + et * 64 + e] = Ts[ff * 65 + e];
    }
}

// ---------------------------------------------------------------------------
// Transpose v: vb[bh][s][d] bf16 -> vt[bh][d][s] bf16. grid (16 s-tiles, 128 bh).
// ---------------------------------------------------------------------------
__global__ __launch_bounds__(256) void transpose_v_kernel(
    const unsigned short* __restrict__ vb, unsigned short* __restrict__ vt)
{
    __shared__ unsigned short Ts[64 * 65];
    const int st = blockIdx.x, bh = blockIdx.y;
    const size_t ibase = (size_t)bh * S_ * D_;
    const size_t obase = (size_t)bh * D_ * S_;

    const int d = threadIdx.x & 63;
    const int s0 = threadIdx.x >> 6;   // 0..3
    #pragma unroll
    for (int p = 0; p < 16; ++p) {
        const int s = s0 + p * 4;
        const int srow = st * 64 + s;
        Ts[s * 65 + d] = (srow < S_) ? vb[ibase + (size_t)srow * D_ + d] : 0;
    }
    __syncthreads();
    const int s = threadIdx.x & 63;
    const int d0 = threadIdx.x >> 6;
    const int scol = st * 64 + s;
    if (scol < S_) {
        #pragma unroll
        for (int p = 0; p < 16; ++p) {
            const int dd = d0 + p * 4;
            vt[obase + (size_t)dd * S_ + scol] = Ts[s * 65 + dd];
        }
    }
}

// ---------------------------------------------------------------------------
// qkv projection, bf16 MFMA v2. grid = (63, H), block 256 = 4 waves as 2m x 2n.
// Block tile 128 rows x 192 cols; each wave 64 rows x 96 cols.
// Register-prefetch of the next K-tile overlaps global latency with MFMA.
// ---------------------------------------------------------------------------
__global__ __launch_bounds__(256) void qkv_mfma_kernel(
    const unsigned short* __restrict__ xbf, const unsigned short* __restrict__ WT,
    const float* __restrict__ bq, const float* __restrict__ bk,
    const float* __restrict__ bv,
    unsigned short* __restrict__ qb, unsigned short* __restrict__ kb,
    unsigned short* __restrict__ vb)
{
    constexpr int P = 72;
    __shared__ unsigned short As[128 * P];      // 18.4 KB
    __shared__ unsigned short Bs[3 * 64 * P];   // 27.6 KB

    const int tid = threadIdx.x;
    const int wave = tid >> 6, lane = tid & 63;
    const int m16 = lane & 15, quad = lane >> 4;
    const int wm = wave >> 1, wn = wave & 1;
    const int m0 = blockIdx.x * 128;
    const int h  = blockIdx.y;

    f32x4 acc[6][4];   // [n-frag][m-frag]
    #pragma unroll
    for (int nf = 0; nf < 6; ++nf)
        #pragma unroll
        for (int mf = 0; mf < 4; ++mf)
            acc[nf][mf] = (f32x4){0.f, 0.f, 0.f, 0.f};

    // B-frag LDS base offsets for this wave's 6 n-frags
    int boff[6];
    #pragma unroll
    for (int nf = 0; nf < 6; ++nf) {
        const int cc = wn * 96 + nf * 16;
        boff[6 - 1 - (5 - nf)] = (cc >> 6) * 64 * P + (cc & 63) * P;   // = boff[nf]
    }

    // staging coords (A tile 128x64, B tiles 3x 64x64)
    const int ar = tid & 31;
    const int ac8 = (tid >> 5) * 8;
    const int bd = tid & 63;
    const int bc8 = (tid >> 6) * 8;

    // source row clamp for A
    int asrow[4];
    #pragma unroll
    for (int p = 0; p < 4; ++p) {
        int r = m0 + ar + p * 32;
        asrow[p] = (r < M_) ? r : (M_ - 1);
    }

    // prefetch kk = 0
    u16x8 areg[4], breg[3][2];
    #pragma unroll
    for (int p = 0; p < 4; ++p)
        areg[p] = *(const u16x8*)(xbf + (size_t)asrow[p] * E_ + ac8);
    #pragma unroll
    for (int z = 0; z < 3; ++z) {
        const unsigned short* wb = WT + ((size_t)(z * 16 + h) * 64 + bd) * E_;
        breg[z][0] = *(const u16x8*)(wb + bc8);
        breg[z][1] = *(const u16x8*)(wb + bc8 + 32);
    }

    for (int kk = 0; kk < E_; kk += 64) {
        __syncthreads();   // all waves done reading LDS from previous iter
        #pragma unroll
        for (int p = 0; p < 4; ++p)
            *(u16x8*)&As[(ar + p * 32) * P + ac8] = areg[p];
        #pragma unroll
        for (int z = 0; z < 3; ++z) {
            *(u16x8*)&Bs[z * 64 * P + bd * P + bc8]      = breg[z][0];
            *(u16x8*)&Bs[z * 64 * P + bd * P + bc8 + 32] = breg[z][1];
        }
        __syncthreads();   // staging visible

        // issue next K-tile's global loads; they complete during compute
        if (kk + 64 < E_) {
            const int kn = kk + 64;
            #pragma unroll
            for (int p = 0; p < 4; ++p)
                areg[p] = *(const u16x8*)(xbf + (size_t)asrow[p] * E_ + kn + ac8);
            #pragma unroll
            for (int z = 0; z < 3; ++z) {
                const unsigned short* wb = WT + ((size_t)(z * 16 + h) * 64 + bd) * E_ + kn;
                breg[z][0] = *(const u16x8*)(wb + bc8);
                breg[z][1] = *(const u16x8*)(wb + bc8 + 32);
            }
        }

        #pragma unroll
        for (int kh = 0; kh < 2; ++kh) {
            const int ko = kh * 32 + quad * 8;
            bf16x8 af[4];
            #pragma unroll
            for (int mf = 0; mf < 4; ++mf)
                af[mf] = *(const bf16x8*)&As[(wm * 64 + mf * 16 + m16) * P + ko];
            #pragma unroll
            for (int nf = 0; nf < 6; ++nf) {
                const bf16x8 bfr = *(const bf16x8*)&Bs[boff[nf] + m16 * P + ko];
                #pragma unroll
                for (int mf = 0; mf < 4; ++mf)
                    acc[nf][mf] = __builtin_amdgcn_mfma_f32_16x16x32_bf16(
                        af[mf], bfr, acc[nf][mf], 0, 0, 0);
            }
        }
    }

    // ---- epilogue ----
    // per-nf output buffer / bias / d-offset
    #pragma unroll
    for (int nf = 0; nf < 6; ++nf) {
        const int cc = wn * 96 + nf * 16;
        const int zz = cc >> 6;
        const int dd = (cc & 63) + m16;
        unsigned short* const op = (zz == 0) ? qb : (zz == 1) ? kb : vb;
        const float* const bp_  = (zz == 0) ? bq : (zz == 1) ? bk : bv;
        const float biasv = bp_[h * D_ + dd];
        #pragma unroll
        for (int mf = 0; mf < 4; ++mf)
            #pragma unroll
            for (int r = 0; r < 4; ++r) {
                const int row = m0 + wm * 64 + mf * 16 + quad * 4 + r;
                if (row < M_) {
                    const int b = row / S_, s = row % S_;
                    op[(((size_t)b * H_ + h) * S_ + s) * D_ + dd] =
                        f2bf(acc[nf][mf][r] + biasv);
                }
            }
    }
}

// ---------------------------------------------------------------------------
// Flash attention (unchanged from round 8).
// ---------------------------------------------------------------------------
__global__ __launch_bounds__(256) void attn_flash_kernel(
    const unsigned short* __restrict__ q, const unsigned short* __restrict__ k,
    const unsigned short* __restrict__ vt, unsigned short* __restrict__ ybf)
{
    constexpr int P_ = 72;
    __shared__ unsigned short Qs[64 * P_];
    __shared__ unsigned short Ks[64 * P_];
    __shared__ unsigned short Vt[64 * P_];   // [d][t]
    __shared__ unsigned short Ps[4][16 * P_];

    const int tid  = threadIdx.x;
    const int wave = tid >> 6, lane = tid & 63;
    const int m16  = lane & 15, quad = lane >> 4;
    const int qt = (int)gridDim.x - 1 - (int)blockIdx.x;   // long blocks first
    const int h = blockIdx.y, b = blockIdx.z;
    const size_t bh  = ((size_t)b * H_ + h) * S_;
    const size_t vtb = ((size_t)b * H_ + h) * (size_t)D_ * S_;
    const float sl2e = 0.031622776601683794f * 1.4426950408889634f;

    const int c8 = (tid & 7) * 8;
    const int r0 = tid >> 3;   // 0..31

    #pragma unroll
    for (int rr = 0; rr < 64; rr += 32) {
        const int r = r0 + rr;
        const int srow = qt * 64 + r;
        u16x8 val = {0, 0, 0, 0, 0, 0, 0, 0};
        if (srow < S_) val = *(const u16x8*)(q + (bh + srow) * D_ + c8);
        u16x8 o;
        #pragma unroll
        for (int j = 0; j < 8; ++j) o[j] = f2bf_fast(bfr2f(val[j]) * sl2e);
        *(u16x8*)&Qs[r * P_ + c8] = o;
    }
    __syncthreads();

    const bf16x8 qa0 = *(const bf16x8*)&Qs[(wave * 16 + m16) * P_ + quad * 8];
    const bf16x8 qa1 = *(const bf16x8*)&Qs[(wave * 16 + m16) * P_ + 32 + quad * 8];

    f32x4 O[4] = {{0,0,0,0},{0,0,0,0},{0,0,0,0},{0,0,0,0}};
    float l_i[4] = {0.f, 0.f, 0.f, 0.f};

    const int qrow_base = qt * 64 + wave * 16 + quad * 4;

    u16x8 kreg[2], vreg[2];
    #pragma unroll
    for (int i = 0; i < 2; ++i) {
        const int srow = r0 + i * 32;
        kreg[i] = *(const u16x8*)(k + (bh + srow) * D_ + c8);
        vreg[i] = *(const u16x8*)(vt + vtb + (size_t)(r0 + i * 32) * S_ + c8);
    }

    for (int tt = 0; tt <= qt; ++tt) {
        const int t0 = tt * 64;
        __syncthreads();
        #pragma unroll
        for (int i = 0; i < 2; ++i) {
            *(u16x8*)&Ks[(r0 + i * 32) * P_ + c8] = kreg[i];
            *(u16x8*)&Vt[(r0 + i * 32) * P_ + c8] = vreg[i];
        }
        __syncthreads();

        if (tt < qt) {
            const int nt0 = t0 + 64;
            #pragma unroll
            for (int i = 0; i < 2; ++i) {
                const int t = r0 + i * 32;
                const int srow = nt0 + t;
                u16x8 kv = {0,0,0,0,0,0,0,0}, vv = {0,0,0,0,0,0,0,0};
                if (srow < S_) kv = *(const u16x8*)(k + (bh + srow) * D_ + c8);
                if (nt0 + c8 < S_)
                    vv = *(const u16x8*)(vt + vtb + (size_t)t * S_ + nt0 + c8);
                kreg[i] = kv; vreg[i] = vv;
            }
        }

        f32x4 sc[4];
        #pragma unroll
        for (int ts = 0; ts < 4; ++ts) {
            const bf16x8 kb0 = *(const bf16x8*)&Ks[(ts * 16 + m16) * P_ + quad * 8];
            const bf16x8 kb1 = *(const bf16x8*)&Ks[(ts * 16 + m16) * P_ + 32 + quad * 8];
            f32x4 a = {0.f, 0.f, 0.f, 0.f};
            a = __builtin_amdgcn_mfma_f32_16x16x32_bf16(qa0, kb0, a, 0, 0, 0);
            a = __builtin_amdgcn_mfma_f32_16x16x32_bf16(qa1, kb1, a, 0, 0, 0);
            sc[ts] = a;
        }

        unsigned short* const pw = &Ps[wave][0];
        if (tt == qt) {
            #pragma unroll
            for (int ts = 0; ts < 4; ++ts) {
                const int t = t0 + ts * 16 + m16;
                #pragma unroll
                for (int r = 0; r < 4; ++r) {
                    float p = __builtin_amdgcn_exp2f(sc[ts][r]);
                    p = (t <= qrow_base + r) ? p : 0.f;
                    pw[(quad * 4 + r) * P_ + ts * 16 + m16] = f2bf_fast(p);
                    l_i[r] += p;
                }
            }
        } else {
            #pragma unroll
            for (int ts = 0; ts < 4; ++ts)
                #pragma unroll
                for (int r = 0; r < 4; ++r) {
                    const float p = __builtin_amdgcn_exp2f(sc[ts][r]);
                    pw[(quad * 4 + r) * P_ + ts * 16 + m16] = f2bf_fast(p);
                    l_i[r] += p;
                }
        }

        const bf16x8 pa0 = *(const bf16x8*)&pw[m16 * P_ + quad * 8];
        const bf16x8 pa1 = *(const bf16x8*)&pw[m16 * P_ + 32 + quad * 8];
        #pragma unroll
        for (int db = 0; db < 4; ++db) {
            const bf16x8 vb0 = *(const bf16x8*)&Vt[(db * 16 + m16) * P_ + quad * 8];
            const bf16x8 vb1 = *(const bf16x8*)&Vt[(db * 16 + m16) * P_ + 32 + quad * 8];
            O[db] = __builtin_amdgcn_mfma_f32_16x16x32_bf16(pa0, vb0, O[db], 0, 0, 0);
            O[db] = __builtin_amdgcn_mfma_f32_16x16x32_bf16(pa1, vb1, O[db], 0, 0, 0);
        }
    }

    #pragma unroll
    for (int off = 1; off < 16; off <<= 1)
        #pragma unroll
        for (int r = 0; r < 4; ++r)
            l_i[r] += __shfl_xor(l_i[r], off, 64);

    #pragma unroll
    for (int r = 0; r < 4; ++r) {
        const int qrow = qrow_base + r;
        if (qrow < S_) {
            const float invl = 1.0f / l_i[r];
            #pragma unroll
            for (int db = 0; db < 4; ++db)
                ybf[((size_t)b * S_ + qrow) * E_ + h * D_ + db * 16 + m16] =
                    f2bf(O[db][r] * invl);
        }
    }
}

// ---------------------------------------------------------------------------
// proj + exact GELU, bf16 MFMA v2. grid = (63, 8), block 256 = 2m x 2n waves.
// Block tile 128x128; each wave 64x64. Register-prefetch pipelining.
// ---------------------------------------------------------------------------
__global__ __launch_bounds__(256) void proj_mfma_kernel(
    const unsigned short* __restrict__ ybf, const unsigned short* __restrict__ wpT,
    const float* __restrict__ bp, float* __restrict__ out)
{
    constexpr int P = 72;
    __shared__ unsigned short As[128 * P];
    __shared__ unsigned short Bs[128 * P];

    const int tid = threadIdx.x;
    const int wave = tid >> 6, lane = tid & 63;
    const int m16 = lane & 15, quad = lane >> 4;
    const int wm = wave >> 1, wn = wave & 1;
    const int m0 = blockIdx.x * 128;
    const int n0 = blockIdx.y * 128;

    f32x4 acc[4][4];
    #pragma unroll
    for (int nf = 0; nf < 4; ++nf)
        #pragma unroll
        for (int mf = 0; mf < 4; ++mf)
            acc[nf][mf] = (f32x4){0.f, 0.f, 0.f, 0.f};

    const int ar = tid & 31;
    const int ac8 = (tid >> 5) * 8;

    int asrow[4];
    #pragma unroll
    for (int p = 0; p < 4; ++p) {
        int r = m0 + ar + p * 32;
        asrow[p] = (r < M_) ? r : (M_ - 1);
    }

    u16x8 areg[4], breg[4];
    #pragma unroll
    for (int p = 0; p < 4; ++p) {
        areg[p] = *(const u16x8*)(ybf + (size_t)asrow[p] * E_ + ac8);
        breg[p] = *(const u16x8*)(wpT + (size_t)(n0 + ar + p * 32) * E_ + ac8);
    }

    for (int kk = 0; kk < E_; kk += 64) {
        __syncthreads();
        #pragma unroll
        for (int p = 0; p < 4; ++p) {
            *(u16x8*)&As[(ar + p * 32) * P + ac8] = areg[p];
            *(u16x8*)&Bs[(ar + p * 32) * P + ac8] = breg[p];
        }
        __syncthreads();

        if (kk + 64 < E_) {
            const int kn = kk + 64;
            #pragma unroll
            for (int p = 0; p < 4; ++p) {
                areg[p] = *(const u16x8*)(ybf + (size_t)asrow[p] * E_ + kn + ac8);
                breg[p] = *(const u16x8*)(wpT + (size_t)(n0 + ar + p * 32) * E_ + kn + ac8);
            }
        }

        #pragma unroll
        for (int kh = 0; kh < 2; ++kh) {
            const int ko = kh * 32 + quad * 8;
            bf16x8 af[4];
            #pragma unroll
            for (int mf = 0; mf < 4; ++mf)
                af[mf] = *(const bf16x8*)&As[(wm * 64 + mf * 16 + m16) * P + ko];
            #pragma unroll
            for (int nf = 0; nf < 4; ++nf) {
                const bf16x8 bfr = *(const bf16x8*)&Bs[(wn * 64 + nf * 16 + m16) * P + ko];
                #pragma unroll
                for (int mf = 0; mf < 4; ++mf)
                    acc[nf][mf] = __builtin_amdgcn_mfma_f32_16x16x32_bf16(
                        af[mf], bfr, acc[nf][mf], 0, 0, 0);
            }
        }
    }

    float biasv[4];
    #pragma unroll
    for (int nf = 0; nf < 4; ++nf)
        biasv[nf] = bp[n0 + wn * 64 + nf * 16 + m16];

    #pragma unroll
    for (int mf = 0; mf < 4; ++mf)
        #pragma unroll
        for (int r = 0; r < 4; ++r) {
            const int row = m0 + wm * 64 + mf * 16 + quad * 4 + r;
            if (row < M_) {
                #pragma unroll
                for (int nf = 0; nf < 4; ++nf) {
                    const int col = n0 + wn * 64 + nf * 16 + m16;
                    const float t = acc[nf][mf][r] + biasv[nf];
                    const float g = 0.5f * t * (1.0f + erff(t * 0.70710678118654752f));
                    out[(size_t)row * E_ + col] = g;
                }
            }
        }
}

// ---------------------------------------------------------------------------
extern "C" void kernel_launch(void* const* d_in, const int* in_sizes, int n_in,
                              void* d_out, int out_size, void* d_ws, size_t ws_size,
                              hipStream_t stream)
{
    const float* x  = (const float*)d_in[0];
    const float* wq = (const float*)d_in[1];
    const float* bq = (const float*)d_in[2];
    const float* wk = (const float*)d_in[3];
    const float* bk = (const float*)d_in[4];
    const float* wv = (const float*)d_in[5];
    const float* bv = (const float*)d_in[6];
    const float* wp = (const float*)d_in[7];
    const float* bp = (const float*)d_in[8];
    float* out = (float*)d_out;

    const size_t nME = (size_t)M_ * E_;          // 8,192,000
    unsigned short* xbf = (unsigned short*)d_ws;
    unsigned short* WT  = xbf + nME;             // 3,145,728
    unsigned short* wpT = WT + 3145728;          // 1,048,576
    unsigned short* qb  = wpT + 1048576;
    unsigned short* kb  = qb + nME;
    unsigned short* vb  = kb + nME;
    unsigned short* ybf = vb + nME;
    unsigned short* vtr = ybf + nME;             // v transposed [bh][d][S]

    cast_x_kernel<<<dim3((unsigned)(nME / 1024)), 256, 0, stream>>>(x, xbf);
    transpose_wqkv_kernel<<<dim3(16, 48), 256, 0, stream>>>(wq, wk, wv, WT);
    transpose_wp_kernel<<<dim3(16, 16), 256, 0, stream>>>(wp, wpT);

    qkv_mfma_kernel<<<dim3((M_ + 127) / 128, H_), 256, 0, stream>>>(
        xbf, WT, bq, bk, bv, qb, kb, vb);
    transpose_v_kernel<<<dim3(16, B_ * H_), 256, 0, stream>>>(vb, vtr);
    attn_flash_kernel<<<dim3((S_ + 63) / 64, H_, B_), 256, 0, stream>>>(
        qb, kb, vtr, ybf);
    proj_mfma_kernel<<<dim3((M_ + 127) / 128, E_ / 128), 256, 0, stream>>>(
        ybf, wpT, bp, out);
}

// Round 10
// 309.685 us; speedup vs baseline: 1.2252x; 1.2252x over previous
//
#include <hip/hip_runtime.h>
#include <hip/hip_bf16.h>
#include <math.h>

// Problem constants: B=8, S=1000, E=1024, H=16, D=64
constexpr int B_ = 8, S_ = 1000, E_ = 1024, H_ = 16, D_ = 64;
constexpr int M_ = B_ * S_;   // 8000 rows

using bf16x8 = __attribute__((ext_vector_type(8))) __bf16;
using u16x8  = __attribute__((ext_vector_type(8))) unsigned short;
using f32x4  = __attribute__((ext_vector_type(4))) float;

static __device__ __forceinline__ unsigned short f2bf(float f) {
    union { float f; unsigned u; } c; c.f = f;
    return (unsigned short)((c.u + 0x7FFF + ((c.u >> 16) & 1)) >> 16);
}
static __device__ __forceinline__ unsigned short f2bf_fast(float f) {
    union { float f; unsigned u; } c; c.f = f;
    return (unsigned short)((c.u + 0x8000) >> 16);   // round-half-up
}
static __device__ __forceinline__ float bfr2f(unsigned short s) {
    union { unsigned u; float f; } c; c.u = ((unsigned)s) << 16;
    return c.f;
}

// ---------------------------------------------------------------------------
// Cast x (fp32 [M,E]) -> bf16.
// ---------------------------------------------------------------------------
__global__ __launch_bounds__(256) void cast_x_kernel(
    const float* __restrict__ x, unsigned short* __restrict__ xbf)
{
    const size_t i = ((size_t)blockIdx.x * 256 + threadIdx.x) * 4;
    float4 v = *(const float4*)(x + i);
    ushort4 o;
    o.x = f2bf(v.x); o.y = f2bf(v.y); o.z = f2bf(v.z); o.w = f2bf(v.w);
    *(ushort4*)(xbf + i) = o;
}

// ---------------------------------------------------------------------------
// Transpose+cast qkv weights: w[h][e][d] fp32 -> WT[(z*16+h)*64 + d][e] bf16.
// ---------------------------------------------------------------------------
__global__ __launch_bounds__(256) void transpose_wqkv_kernel(
    const float* __restrict__ wq, const float* __restrict__ wk,
    const float* __restrict__ wv, unsigned short* __restrict__ WT)
{
    __shared__ unsigned short Ts[64 * 65];
    const int et = blockIdx.x, zh = blockIdx.y;
    const int z = zh >> 4, h = zh & 15;
    const float* src = (z == 0 ? wq : z == 1 ? wk : wv) + (size_t)h * E_ * D_;

    const int d = threadIdx.x & 63;
    const int e0 = threadIdx.x >> 6;   // 0..3
    #pragma unroll
    for (int p = 0; p < 16; ++p) {
        const int e = e0 + p * 4;
        Ts[d * 65 + e] = f2bf(src[(size_t)(et * 64 + e) * D_ + d]);
    }
    __syncthreads();
    const int e = threadIdx.x & 63;
    const int d0 = threadIdx.x >> 6;
    #pragma unroll
    for (int p = 0; p < 16; ++p) {
        const int dd = d0 + p * 4;
        WT[((size_t)zh * 64 + dd) * E_ + et * 64 + e] = Ts[dd * 65 + e];
    }
}

// ---------------------------------------------------------------------------
// Transpose+cast wp: wp[e][f] fp32 -> wpT[f][e] bf16. grid (16 e, 16 f).
// ---------------------------------------------------------------------------
__global__ __launch_bounds__(256) void transpose_wp_kernel(
    const float* __restrict__ wp, unsigned short* __restrict__ wpT)
{
    __shared__ unsigned short Ts[64 * 65];
    const int et = blockIdx.x, ft = blockIdx.y;
    const int f = threadIdx.x & 63;
    const int e0 = threadIdx.x >> 6;
    #pragma unroll
    for (int p = 0; p < 16; ++p) {
        const int e = e0 + p * 4;
        Ts[f * 65 + e] = f2bf(wp[(size_t)(et * 64 + e) * E_ + ft * 64 + f]);
    }
    __syncthreads();
    const int e = threadIdx.x & 63;
    const int f0 = threadIdx.x >> 6;
    #pragma unroll
    for (int p = 0; p < 16; ++p) {
        const int ff = f0 + p * 4;
        wpT[((size_t)(ft * 64 + ff)) * E_ + et * 64 + e] = Ts[ff * 65 + e];
    }
}

// ---------------------------------------------------------------------------
// Transpose v: vb[bh][s][d] bf16 -> vt[bh][d][s] bf16. grid (16 s-tiles, 128 bh).
// ---------------------------------------------------------------------------
__global__ __launch_bounds__(256) void transpose_v_kernel(
    const unsigned short* __restrict__ vb, unsigned short* __restrict__ vt)
{
    __shared__ unsigned short Ts[64 * 65];
    const int st = blockIdx.x, bh = blockIdx.y;
    const size_t ibase = (size_t)bh * S_ * D_;
    const size_t obase = (size_t)bh * D_ * S_;

    const int d = threadIdx.x & 63;
    const int s0 = threadIdx.x >> 6;   // 0..3
    #pragma unroll
    for (int p = 0; p < 16; ++p) {
        const int s = s0 + p * 4;
        const int srow = st * 64 + s;
        Ts[s * 65 + d] = (srow < S_) ? vb[ibase + (size_t)srow * D_ + d] : 0;
    }
    __syncthreads();
    const int s = threadIdx.x & 63;
    const int d0 = threadIdx.x >> 6;
    const int scol = st * 64 + s;
    if (scol < S_) {
        #pragma unroll
        for (int p = 0; p < 16; ++p) {
            const int dd = d0 + p * 4;
            vt[obase + (size_t)dd * S_ + scol] = Ts[s * 65 + dd];
        }
    }
}

// ---------------------------------------------------------------------------
// qkv projection, bf16 MFMA (round-8 structure — empirically fastest).
// grid = (ceil(M/128)=63, H), block 256 (4 waves, each 32 rows x 192 cols).
// Inline global->LDS staging; compiler interleaves partial-vmcnt waits.
// NOTE: R9's 2m x 2n wave remap + register prefetch REGRESSED this kernel
// (97.5 -> 164.9 us, MfmaUtil 21 -> 12%) — do not reapply without new theory.
// ---------------------------------------------------------------------------
__global__ __launch_bounds__(256) void qkv_mfma_kernel(
    const unsigned short* __restrict__ xbf, const unsigned short* __restrict__ WT,
    const float* __restrict__ bq, const float* __restrict__ bk,
    const float* __restrict__ bv,
    unsigned short* __restrict__ qb, unsigned short* __restrict__ kb,
    unsigned short* __restrict__ vb)
{
    constexpr int P = 72;
    __shared__ unsigned short As[128 * P];      // 18.4 KB
    __shared__ unsigned short Bs[3][64 * P];    // 27.6 KB

    const int tid = threadIdx.x;
    const int wave = tid >> 6, lane = tid & 63;
    const int m16 = lane & 15, quad = lane >> 4;
    const int m0 = blockIdx.x * 128;
    const int h  = blockIdx.y;

    f32x4 acc[3][4][2];   // [z][n-frag][m-half]
    #pragma unroll
    for (int z = 0; z < 3; ++z)
        #pragma unroll
        for (int nt = 0; nt < 4; ++nt)
            #pragma unroll
            for (int mh = 0; mh < 2; ++mh)
                acc[z][nt][mh] = (f32x4){0.f, 0.f, 0.f, 0.f};

    // staging coords
    const int ar = tid & 31;              // A row base
    const int ac8 = (tid >> 5) * 8;       // A col block
    const int bd = tid & 63;              // B row (d)
    const int bc8 = (tid >> 6) * 8;       // B col blocks: bc8, bc8+32

    for (int kk = 0; kk < E_; kk += 64) {
        __syncthreads();
        #pragma unroll
        for (int p = 0; p < 4; ++p) {
            const int r = ar + p * 32;
            int srow = m0 + r; if (srow >= M_) srow = M_ - 1;
            *(u16x8*)&As[r * P + ac8] =
                *(const u16x8*)(xbf + (size_t)srow * E_ + kk + ac8);
        }
        #pragma unroll
        for (int z = 0; z < 3; ++z) {
            const unsigned short* wb = WT + ((size_t)(z * 16 + h) * 64 + bd) * E_ + kk;
            *(u16x8*)&Bs[z][bd * P + bc8]      = *(const u16x8*)(wb + bc8);
            *(u16x8*)&Bs[z][bd * P + bc8 + 32] = *(const u16x8*)(wb + bc8 + 32);
        }
        __syncthreads();

        #pragma unroll
        for (int kh = 0; kh < 2; ++kh) {
            const int ko = kh * 32 + quad * 8;
            const bf16x8 a0 = *(const bf16x8*)&As[(wave * 32 + m16) * P + ko];
            const bf16x8 a1 = *(const bf16x8*)&As[(wave * 32 + 16 + m16) * P + ko];
            #pragma unroll
            for (int z = 0; z < 3; ++z)
                #pragma unroll
                for (int nt = 0; nt < 4; ++nt) {
                    const bf16x8 bfr = *(const bf16x8*)&Bs[z][(nt * 16 + m16) * P + ko];
                    acc[z][nt][0] = __builtin_amdgcn_mfma_f32_16x16x32_bf16(a0, bfr, acc[z][nt][0], 0, 0, 0);
                    acc[z][nt][1] = __builtin_amdgcn_mfma_f32_16x16x32_bf16(a1, bfr, acc[z][nt][1], 0, 0, 0);
                }
        }
    }

    float biasv[3][4];
    #pragma unroll
    for (int nt = 0; nt < 4; ++nt) {
        biasv[0][nt] = bq[h * D_ + nt * 16 + m16];
        biasv[1][nt] = bk[h * D_ + nt * 16 + m16];
        biasv[2][nt] = bv[h * D_ + nt * 16 + m16];
    }

    #pragma unroll
    for (int mh = 0; mh < 2; ++mh)
        #pragma unroll
        for (int r = 0; r < 4; ++r) {
            const int row = m0 + wave * 32 + mh * 16 + quad * 4 + r;
            if (row < M_) {
                const int b = row / S_, s = row % S_;
                const size_t ob = (((size_t)b * H_ + h) * S_ + s) * D_ + m16;
                #pragma unroll
                for (int nt = 0; nt < 4; ++nt) {
                    qb[ob + nt * 16] = f2bf(acc[0][nt][mh][r] + biasv[0][nt]);
                    kb[ob + nt * 16] = f2bf(acc[1][nt][mh][r] + biasv[1][nt]);
                    vb[ob + nt * 16] = f2bf(acc[2][nt][mh][r] + biasv[2][nt]);
                }
            }
        }
}

// ---------------------------------------------------------------------------
// Flash attention (unchanged from round 8).
// ---------------------------------------------------------------------------
__global__ __launch_bounds__(256) void attn_flash_kernel(
    const unsigned short* __restrict__ q, const unsigned short* __restrict__ k,
    const unsigned short* __restrict__ vt, unsigned short* __restrict__ ybf)
{
    constexpr int P_ = 72;
    __shared__ unsigned short Qs[64 * P_];
    __shared__ unsigned short Ks[64 * P_];
    __shared__ unsigned short Vt[64 * P_];   // [d][t]
    __shared__ unsigned short Ps[4][16 * P_];

    const int tid  = threadIdx.x;
    const int wave = tid >> 6, lane = tid & 63;
    const int m16  = lane & 15, quad = lane >> 4;
    const int qt = (int)gridDim.x - 1 - (int)blockIdx.x;   // long blocks first
    const int h = blockIdx.y, b = blockIdx.z;
    const size_t bh  = ((size_t)b * H_ + h) * S_;
    const size_t vtb = ((size_t)b * H_ + h) * (size_t)D_ * S_;
    const float sl2e = 0.031622776601683794f * 1.4426950408889634f;

    const int c8 = (tid & 7) * 8;
    const int r0 = tid >> 3;   // 0..31

    #pragma unroll
    for (int rr = 0; rr < 64; rr += 32) {
        const int r = r0 + rr;
        const int srow = qt * 64 + r;
        u16x8 val = {0, 0, 0, 0, 0, 0, 0, 0};
        if (srow < S_) val = *(const u16x8*)(q + (bh + srow) * D_ + c8);
        u16x8 o;
        #pragma unroll
        for (int j = 0; j < 8; ++j) o[j] = f2bf_fast(bfr2f(val[j]) * sl2e);
        *(u16x8*)&Qs[r * P_ + c8] = o;
    }
    __syncthreads();

    const bf16x8 qa0 = *(const bf16x8*)&Qs[(wave * 16 + m16) * P_ + quad * 8];
    const bf16x8 qa1 = *(const bf16x8*)&Qs[(wave * 16 + m16) * P_ + 32 + quad * 8];

    f32x4 O[4] = {{0,0,0,0},{0,0,0,0},{0,0,0,0},{0,0,0,0}};
    float l_i[4] = {0.f, 0.f, 0.f, 0.f};

    const int qrow_base = qt * 64 + wave * 16 + quad * 4;

    u16x8 kreg[2], vreg[2];
    #pragma unroll
    for (int i = 0; i < 2; ++i) {
        const int srow = r0 + i * 32;
        kreg[i] = *(const u16x8*)(k + (bh + srow) * D_ + c8);
        vreg[i] = *(const u16x8*)(vt + vtb + (size_t)(r0 + i * 32) * S_ + c8);
    }

    for (int tt = 0; tt <= qt; ++tt) {
        const int t0 = tt * 64;
        __syncthreads();
        #pragma unroll
        for (int i = 0; i < 2; ++i) {
            *(u16x8*)&Ks[(r0 + i * 32) * P_ + c8] = kreg[i];
            *(u16x8*)&Vt[(r0 + i * 32) * P_ + c8] = vreg[i];
        }
        __syncthreads();

        if (tt < qt) {
            const int nt0 = t0 + 64;
            #pragma unroll
            for (int i = 0; i < 2; ++i) {
                const int t = r0 + i * 32;
                const int srow = nt0 + t;
                u16x8 kv = {0,0,0,0,0,0,0,0}, vv = {0,0,0,0,0,0,0,0};
                if (srow < S_) kv = *(const u16x8*)(k + (bh + srow) * D_ + c8);
                if (nt0 + c8 < S_)
                    vv = *(const u16x8*)(vt + vtb + (size_t)t * S_ + nt0 + c8);
                kreg[i] = kv; vreg[i] = vv;
            }
        }

        f32x4 sc[4];
        #pragma unroll
        for (int ts = 0; ts < 4; ++ts) {
            const bf16x8 kb0 = *(const bf16x8*)&Ks[(ts * 16 + m16) * P_ + quad * 8];
            const bf16x8 kb1 = *(const bf16x8*)&Ks[(ts * 16 + m16) * P_ + 32 + quad * 8];
            f32x4 a = {0.f, 0.f, 0.f, 0.f};
            a = __builtin_amdgcn_mfma_f32_16x16x32_bf16(qa0, kb0, a, 0, 0, 0);
            a = __builtin_amdgcn_mfma_f32_16x16x32_bf16(qa1, kb1, a, 0, 0, 0);
            sc[ts] = a;
        }

        unsigned short* const pw = &Ps[wave][0];
        if (tt == qt) {
            #pragma unroll
            for (int ts = 0; ts < 4; ++ts) {
                const int t = t0 + ts * 16 + m16;
                #pragma unroll
                for (int r = 0; r < 4; ++r) {
                    float p = __builtin_amdgcn_exp2f(sc[ts][r]);
                    p = (t <= qrow_base + r) ? p : 0.f;
                    pw[(quad * 4 + r) * P_ + ts * 16 + m16] = f2bf_fast(p);
                    l_i[r] += p;
                }
            }
        } else {
            #pragma unroll
            for (int ts = 0; ts < 4; ++ts)
                #pragma unroll
                for (int r = 0; r < 4; ++r) {
                    const float p = __builtin_amdgcn_exp2f(sc[ts][r]);
                    pw[(quad * 4 + r) * P_ + ts * 16 + m16] = f2bf_fast(p);
                    l_i[r] += p;
                }
        }

        const bf16x8 pa0 = *(const bf16x8*)&pw[m16 * P_ + quad * 8];
        const bf16x8 pa1 = *(const bf16x8*)&pw[m16 * P_ + 32 + quad * 8];
        #pragma unroll
        for (int db = 0; db < 4; ++db) {
            const bf16x8 vb0 = *(const bf16x8*)&Vt[(db * 16 + m16) * P_ + quad * 8];
            const bf16x8 vb1 = *(const bf16x8*)&Vt[(db * 16 + m16) * P_ + 32 + quad * 8];
            O[db] = __builtin_amdgcn_mfma_f32_16x16x32_bf16(pa0, vb0, O[db], 0, 0, 0);
            O[db] = __builtin_amdgcn_mfma_f32_16x16x32_bf16(pa1, vb1, O[db], 0, 0, 0);
        }
    }

    #pragma unroll
    for (int off = 1; off < 16; off <<= 1)
        #pragma unroll
        for (int r = 0; r < 4; ++r)
            l_i[r] += __shfl_xor(l_i[r], off, 64);

    #pragma unroll
    for (int r = 0; r < 4; ++r) {
        const int qrow = qrow_base + r;
        if (qrow < S_) {
            const float invl = 1.0f / l_i[r];
            #pragma unroll
            for (int db = 0; db < 4; ++db)
                ybf[((size_t)b * S_ + qrow) * E_ + h * D_ + db * 16 + m16] =
                    f2bf(O[db][r] * invl);
        }
    }
}

// ---------------------------------------------------------------------------
// proj + exact GELU, bf16 MFMA v2 (kept from round 9). grid = (63, 8),
// block 256 = 2m x 2n waves; block tile 128x128; register-prefetch.
// ---------------------------------------------------------------------------
__global__ __launch_bounds__(256) void proj_mfma_kernel(
    const unsigned short* __restrict__ ybf, const unsigned short* __restrict__ wpT,
    const float* __restrict__ bp, float* __restrict__ out)
{
    constexpr int P = 72;
    __shared__ unsigned short As[128 * P];
    __shared__ unsigned short Bs[128 * P];

    const int tid = threadIdx.x;
    const int wave = tid >> 6, lane = tid & 63;
    const int m16 = lane & 15, quad = lane >> 4;
    const int wm = wave >> 1, wn = wave & 1;
    const int m0 = blockIdx.x * 128;
    const int n0 = blockIdx.y * 128;

    f32x4 acc[4][4];
    #pragma unroll
    for (int nf = 0; nf < 4; ++nf)
        #pragma unroll
        for (int mf = 0; mf < 4; ++mf)
            acc[nf][mf] = (f32x4){0.f, 0.f, 0.f, 0.f};

    const int ar = tid & 31;
    const int ac8 = (tid >> 5) * 8;

    int asrow[4];
    #pragma unroll
    for (int p = 0; p < 4; ++p) {
        int r = m0 + ar + p * 32;
        asrow[p] = (r < M_) ? r : (M_ - 1);
    }

    u16x8 areg[4], breg[4];
    #pragma unroll
    for (int p = 0; p < 4; ++p) {
        areg[p] = *(const u16x8*)(ybf + (size_t)asrow[p] * E_ + ac8);
        breg[p] = *(const u16x8*)(wpT + (size_t)(n0 + ar + p * 32) * E_ + ac8);
    }

    for (int kk = 0; kk < E_; kk += 64) {
        __syncthreads();
        #pragma unroll
        for (int p = 0; p < 4; ++p) {
            *(u16x8*)&As[(ar + p * 32) * P + ac8] = areg[p];
            *(u16x8*)&Bs[(ar + p * 32) * P + ac8] = breg[p];
        }
        __syncthreads();

        if (kk + 64 < E_) {
            const int kn = kk + 64;
            #pragma unroll
            for (int p = 0; p < 4; ++p) {
                areg[p] = *(const u16x8*)(ybf + (size_t)asrow[p] * E_ + kn + ac8);
                breg[p] = *(const u16x8*)(wpT + (size_t)(n0 + ar + p * 32) * E_ + kn + ac8);
            }
        }

        #pragma unroll
        for (int kh = 0; kh < 2; ++kh) {
            const int ko = kh * 32 + quad * 8;
            bf16x8 af[4];
            #pragma unroll
            for (int mf = 0; mf < 4; ++mf)
                af[mf] = *(const bf16x8*)&As[(wm * 64 + mf * 16 + m16) * P + ko];
            #pragma unroll
            for (int nf = 0; nf < 4; ++nf) {
                const bf16x8 bfr = *(const bf16x8*)&Bs[(wn * 64 + nf * 16 + m16) * P + ko];
                #pragma unroll
                for (int mf = 0; mf < 4; ++mf)
                    acc[nf][mf] = __builtin_amdgcn_mfma_f32_16x16x32_bf16(
                        af[mf], bfr, acc[nf][mf], 0, 0, 0);
            }
        }
    }

    float biasv[4];
    #pragma unroll
    for (int nf = 0; nf < 4; ++nf)
        biasv[nf] = bp[n0 + wn * 64 + nf * 16 + m16];

    #pragma unroll
    for (int mf = 0; mf < 4; ++mf)
        #pragma unroll
        for (int r = 0; r < 4; ++r) {
            const int row = m0 + wm * 64 + mf * 16 + quad * 4 + r;
            if (row < M_) {
                #pragma unroll
                for (int nf = 0; nf < 4; ++nf) {
                    const int col = n0 + wn * 64 + nf * 16 + m16;
                    const float t = acc[nf][mf][r] + biasv[nf];
                    const float g = 0.5f * t * (1.0f + erff(t * 0.70710678118654752f));
                    out[(size_t)row * E_ + col] = g;
                }
            }
        }
}

// ---------------------------------------------------------------------------
extern "C" void kernel_launch(void* const* d_in, const int* in_sizes, int n_in,
                              void* d_out, int out_size, void* d_ws, size_t ws_size,
                              hipStream_t stream)
{
    const float* x  = (const float*)d_in[0];
    const float* wq = (const float*)d_in[1];
    const float* bq = (const float*)d_in[2];
    const float* wk = (const float*)d_in[3];
    const float* bk = (const float*)d_in[4];
    const float* wv = (const float*)d_in[5];
    const float* bv = (const float*)d_in[6];
    const float* wp = (const float*)d_in[7];
    const float* bp = (const float*)d_in[8];
    float* out = (float*)d_out;

    const size_t nME = (size_t)M_ * E_;          // 8,192,000
    unsigned short* xbf = (unsigned short*)d_ws;
    unsigned short* WT  = xbf + nME;             // 3,145,728
    unsigned short* wpT = WT + 3145728;          // 1,048,576
    unsigned short* qb  = wpT + 1048576;
    unsigned short* kb  = qb + nME;
    unsigned short* vb  = kb + nME;
    unsigned short* ybf = vb + nME;
    unsigned short* vtr = ybf + nME;             // v transposed [bh][d][S]

    cast_x_kernel<<<dim3((unsigned)(nME / 1024)), 256, 0, stream>>>(x, xbf);
    transpose_wqkv_kernel<<<dim3(16, 48), 256, 0, stream>>>(wq, wk, wv, WT);
    transpose_wp_kernel<<<dim3(16, 16), 256, 0, stream>>>(wp, wpT);

    qkv_mfma_kernel<<<dim3((M_ + 127) / 128, H_), 256, 0, stream>>>(
        xbf, WT, bq, bk, bv, qb, kb, vb);
    transpose_v_kernel<<<dim3(16, B_ * H_), 256, 0, stream>>>(vb, vtr);
    attn_flash_kernel<<<dim3((S_ + 63) / 64, H_, B_), 256, 0, stream>>>(
        qb, kb, vtr, ybf);
    proj_mfma_kernel<<<dim3((M_ + 127) / 128, E_ / 128), 256, 0, stream>>>(
        ybf, wpT, bp, out);
}